// Round 1
// baseline (82.266 us; speedup 1.0000x reference)
//
#include <hip/hip_runtime.h>

// Problem constants (from reference setup_inputs): v, v_pred are [4, 8192, 3] fp32.
#define BB 4
#define NN 8192
#define MM 8192
#define BN (BB * NN)

#define BLK 256      // threads per block
#define P   4        // query points per thread
#define NX  (BLK*P)  // 1024 query points per block
#define MC  512      // target points per y-chunk (LDS staged)
#define S   (MM/MC)  // 16 y-chunks

// Kernel 1: for each (batch b, x-chunk ib, y-chunk s) block, compute
// per-query-point min_{j in chunk} ||x_i - y_j||^2 and write to part[s][b*N+i].
// Trick: d2 = xx + (yy - 2 x.y); z_j = (2y0, 2y1, 2y2, y.y) staged in LDS,
// so inner loop is 3 FMA + 1 min per pair.
__global__ __launch_bounds__(BLK) void chamfer_partial(
    const float* __restrict__ y,    // v      [B, M, 3]  (targets)
    const float* __restrict__ x,    // v_pred [B, N, 3]  (queries)
    float* __restrict__ part)       // [S, B*N]
{
    __shared__ float4 zb[MC];
    const int t  = threadIdx.x;
    const int ib = blockIdx.x;   // x-chunk 0..N/NX-1
    const int s  = blockIdx.y;   // y-chunk 0..S-1
    const int b  = blockIdx.z;   // batch

    // Stage y chunk into LDS as (2y0, 2y1, 2y2, y.y)
    const float* yb = y + ((size_t)b * MM + (size_t)s * MC) * 3;
    for (int j = t; j < MC; j += BLK) {
        float y0 = yb[3*j + 0];
        float y1 = yb[3*j + 1];
        float y2 = yb[3*j + 2];
        zb[j] = make_float4(2.0f*y0, 2.0f*y1, 2.0f*y2,
                            __builtin_fmaf(y2, y2, __builtin_fmaf(y1, y1, y0*y0)));
    }
    __syncthreads();

    // Load P query points per thread into registers
    float x0[P], x1[P], x2[P], xx[P], best[P];
    const float* xb = x + ((size_t)b * NN + (size_t)ib * NX) * 3;
#pragma unroll
    for (int p = 0; p < P; ++p) {
        int i = t + p * BLK;
        x0[p] = xb[3*i + 0];
        x1[p] = xb[3*i + 1];
        x2[p] = xb[3*i + 2];
        xx[p] = __builtin_fmaf(x2[p], x2[p], __builtin_fmaf(x1[p], x1[p], x0[p]*x0[p]));
        best[p] = 3.4e38f;
    }

    // Hot loop: 3 FMA + 1 min per (j, p) pair
#pragma unroll 4
    for (int j = 0; j < MC; ++j) {
        float4 z = zb[j];
#pragma unroll
        for (int p = 0; p < P; ++p) {
            float tt = __builtin_fmaf(-x0[p], z.x, z.w);
            tt = __builtin_fmaf(-x1[p], z.y, tt);
            tt = __builtin_fmaf(-x2[p], z.z, tt);
            best[p] = fminf(best[p], tt);
        }
    }

    // Epilogue: add back xx, write partial mins (coalesced)
    float* po = part + (size_t)s * BN + (size_t)b * NN + (size_t)ib * NX;
#pragma unroll
    for (int p = 0; p < P; ++p) {
        po[t + p * BLK] = best[p] + xx[p];
    }
}

// Kernel 2: per point, min over S chunks; block-level sum -> bsum[block]
__global__ __launch_bounds__(BLK) void reduce_min_sum(
    const float* __restrict__ part,  // [S, B*N]
    float* __restrict__ bsum)        // [BN/BLK]
{
    const int pt = blockIdx.x * BLK + threadIdx.x;  // 0..BN-1
    float m = 3.4e38f;
#pragma unroll
    for (int s = 0; s < S; ++s) {
        m = fminf(m, part[(size_t)s * BN + pt]);
    }
    // wave-64 sum reduce
    for (int off = 32; off > 0; off >>= 1) {
        m += __shfl_down(m, off, 64);
    }
    __shared__ float wsum[BLK / 64];
    const int lane = threadIdx.x & 63;
    const int w    = threadIdx.x >> 6;
    if (lane == 0) wsum[w] = m;
    __syncthreads();
    if (threadIdx.x == 0) {
        float acc = 0.0f;
#pragma unroll
        for (int i = 0; i < BLK / 64; ++i) acc += wsum[i];
        bsum[blockIdx.x] = acc;
    }
}

// Kernel 3: sum 128 block partials, divide by B*N, write scalar out
__global__ __launch_bounds__(128) void final_reduce(
    const float* __restrict__ bsum,  // [128]
    float* __restrict__ out)
{
    const int t = threadIdx.x;  // 128 threads = 2 waves
    float v = bsum[t];
    for (int off = 32; off > 0; off >>= 1) {
        v += __shfl_down(v, off, 64);
    }
    __shared__ float a[2];
    if ((t & 63) == 0) a[t >> 6] = v;
    __syncthreads();
    if (t == 0) out[0] = (a[0] + a[1]) * (1.0f / (float)BN);
}

extern "C" void kernel_launch(void* const* d_in, const int* in_sizes, int n_in,
                              void* d_out, int out_size, void* d_ws, size_t ws_size,
                              hipStream_t stream) {
    // setup_inputs order: d_in[0] = v (targets y), d_in[1] = v_pred (queries x)
    const float* v      = (const float*)d_in[0];
    const float* v_pred = (const float*)d_in[1];
    float* out = (float*)d_out;

    float* part = (float*)d_ws;              // S * BN floats = 2 MB
    float* bsum = part + (size_t)S * BN;     // 128 floats

    dim3 grid1(NN / NX, S, BB);              // (8, 16, 4) = 512 blocks
    chamfer_partial<<<grid1, BLK, 0, stream>>>(v, v_pred, part);

    reduce_min_sum<<<BN / BLK, BLK, 0, stream>>>(part, bsum);

    final_reduce<<<1, 128, 0, stream>>>(bsum, out);
}